// Round 10
// baseline (210.020 us; speedup 1.0000x reference)
//
#include <hip/hip_runtime.h>

#define TEMP    0.5f
#define LOG2E   1.4426950408889634f
#define C2      (LOG2E / TEMP)        /* t = dot * C2 */
#define MSHIFT  160.0f                /* fixed base-2 softmax shift */
#define LN2     0.6931471805599453f
#define NROWS   16384
#define BHALF   8192
#define DDIM    128
#define NCHUNK  2048                  /* prep chunks = 524288/256 */
#define MAINB   512                   /* blocks */

typedef __bf16 bf16x8 __attribute__((ext_vector_type(8)));
typedef float  f32x16 __attribute__((ext_vector_type(16)));
typedef float  f32x2  __attribute__((ext_vector_type(2)));

__device__ __forceinline__ float fexp2(float x) {
#if __has_builtin(__builtin_amdgcn_exp2f)
  return __builtin_amdgcn_exp2f(x);
#else
  return exp2f(x);
#endif
}

__device__ __forceinline__ unsigned short f2bf(float f) {
  unsigned int u = __float_as_uint(f);
  unsigned int r = (u + 0x7FFFu + ((u >> 16) & 1u)) >> 16;  // RNE
  return (unsigned short)r;
}

// ---------------------------------------------------------------------------
// zbF frag-major layout: for row r, k-index k:
//   g = r/32, lo = r%32, khi = k/8, j = k%8
//   short index = g*4096 + khi*256 + lo*8 + j
// A wave's frag load (fixed ks): 64 lanes read a contiguous 1KB block.
//
// SINGLE-KERNEL fusion (round 10). Frozen lessons:
//  * hot loop = r4's measured-best 73.5us (kZ + pk-fma exp). kC C-operand
//    reverted (r9 A/B: +3.5us, 16 persistent regs).
//  * NO exp/MFMA source interleave (r1/r2/r5 spilled: WRITE 1->19-162MB).
//  * NO thin waves (r6: +17us). NO per-block fences during streaming
//    (r7 buffer_inv storm: +47us) — cache maintenance only at phase edges.
//  * prep barrier is WORK-STEALING (gates on chunks-completed, which running
//    blocks always finish) -> deadlock-free at any residency.
// ---------------------------------------------------------------------------

template <bool MASK>
__device__ __forceinline__ void expAcc(const f32x16& acc, f32x2& s, int d, int hi) {
#pragma unroll
  for (int k = 0; k < 8; ++k) {
    f32x2 u;
    u.x = acc[2 * k];
    u.y = acc[2 * k + 1];
    const f32x2 c2v = {C2, C2};
    const f32x2 msv = {-MSHIFT, -MSHIFT};
    u = __builtin_elementwise_fma(u, c2v, msv);       // v_pk_fma_f32
    f32x2 e;
    e.x = fexp2(u.x);
    e.y = fexp2(u.y);
    if (MASK) {
      const int r0 = 2 * k, r1 = 2 * k + 1;
      if (((r0 & 3) + 8 * (r0 >> 2) + 4 * hi) == d) e.x = 0.f;  // C/D reg map
      if (((r1 & 3) + 8 * (r1 >> 2) + 4 * hi) == d) e.y = 0.f;
    }
    s += e;                                            // v_pk_add_f32
  }
}

#define MFMA_ __builtin_amdgcn_mfma_f32_32x32x16_bf16

__global__ __launch_bounds__(256, 2)
void k_all(const float* __restrict__ zi, const float* __restrict__ zj,
           unsigned short* __restrict__ zbF, float* __restrict__ S,
           float* __restrict__ Pp, unsigned int* __restrict__ cnt,
           float* __restrict__ out) {
  __shared__ unsigned int curChunk;
  __shared__ float red[4];

  // ================= phase 1: work-stealing prep =================
  // chunk c: 256 float4-groups t = c*256 + tid of the old k_prep grid.
  unsigned int nmine = 0;
  for (;;) {
    if (threadIdx.x == 0)
      curChunk = __hip_atomic_fetch_add(&cnt[0], 1u, __ATOMIC_RELAXED,
                                        __HIP_MEMORY_SCOPE_AGENT);
    __syncthreads();
    const unsigned int c = curChunk;
    if (c >= NCHUNK) break;

    const int t   = (int)c * 256 + threadIdx.x;
    const int row = t >> 5;
    const int k0  = (t & 31) * 4;
    const float* src = (row < BHALF) ? (zi + (size_t)row * DDIM)
                                     : (zj + (size_t)(row - BHALF) * DDIM);
    float4 v = *reinterpret_cast<const float4*>(src + k0);

    const int g = row >> 5, lo2 = row & 31, khi = k0 >> 3, j0 = k0 & 7;
    ushort4 o;
    o.x = f2bf(v.x); o.y = f2bf(v.y); o.z = f2bf(v.z); o.w = f2bf(v.w);
    *reinterpret_cast<ushort4*>(zbF + (size_t)g * 4096 + khi * 256 + lo2 * 8 + j0) = o;

    float dot = 0.f;
    if (row < BHALF) {
      float4 w = *reinterpret_cast<const float4*>(zj + (size_t)row * DDIM + k0);
      dot = fmaf(v.x, w.x, fmaf(v.y, w.y, fmaf(v.z, w.z, v.w * w.w)));
    }
#pragma unroll
    for (int m = 32; m >= 1; m >>= 1) dot += __shfl_xor(dot, m, 64);
    if ((threadIdx.x & 63) == 0) red[threadIdx.x >> 6] = dot;
    __syncthreads();
    if (threadIdx.x == 0) Pp[c] = red[0] + red[1] + red[2] + red[3];
    if (t < NROWS) S[t] = 0.f;
    ++nmine;
    __syncthreads();                    // red/curChunk reuse next iteration
  }

  // release my chunks' plain stores to the device coherence point (wbl2),
  // then count them done. ONE release per wave, at the phase edge only.
  __builtin_amdgcn_fence(__ATOMIC_RELEASE, "agent");
  __syncthreads();
  if (threadIdx.x == 0 && nmine)
    __hip_atomic_fetch_add(&cnt[1], nmine, __ATOMIC_RELAXED,
                           __HIP_MEMORY_SCOPE_AGENT);

  // wait for ALL chunks (relaxed polls; running blocks always finish claimed
  // chunks -> no deadlock at any residency), then one acquire.
  if (threadIdx.x == 0) {
    while (__hip_atomic_load(&cnt[1], __ATOMIC_RELAXED,
                             __HIP_MEMORY_SCOPE_AGENT) < NCHUNK)
      __builtin_amdgcn_s_sleep(16);
  }
  __syncthreads();
  __builtin_amdgcn_fence(__ATOMIC_ACQUIRE, "agent");

  // ================= phase 2: r4 main loop (exact) =================
  const int wave = threadIdx.x >> 6;
  const int lane = threadIdx.x & 63;
  const int lo = lane & 31;
  const int hi = lane >> 5;
  const int rb = blockIdx.x & 31;       // 32 row blocks of 512 rows
  const int cc = blockIdx.x >> 5;       // 16 col chunks of 1024 cols
  const int row0w = rb * 512 + wave * 128;

  bf16x8 b[4][8];
#pragma unroll
  for (int rt = 0; rt < 4; ++rt) {
    const unsigned short* bp = zbF + (size_t)((row0w >> 5) + rt) * 4096 + hi * 256 + lo * 8;
#pragma unroll
    for (int ks = 0; ks < 8; ++ks)
      b[rt][ks] = *reinterpret_cast<const bf16x8*>(bp + ks * 512);
  }

  const f32x16 kZ = {};                 // zero C-operand (r9: kC regressed)
  f32x2 s[4];
#pragma unroll
  for (int rt = 0; rt < 4; ++rt) { s[rt].x = 0.f; s[rt].y = 0.f; }

  const int c0base = cc * 1024;
  const unsigned short* abase = zbF + (size_t)(c0base >> 5) * 4096 + hi * 256 + lo * 8;

  bf16x8 a[8];
#pragma unroll
  for (int ks = 0; ks < 8; ++ks)
    a[ks] = *reinterpret_cast<const bf16x8*>(abase + ks * 512);

  if (((blockIdx.x ^ wave) & 1) != 0) __builtin_amdgcn_s_sleep(4);

  for (int it = 0; it < 32; ++it) {
    const int c0 = c0base + it * 32;
    const int dr = c0 - row0w;
    const bool dg = (unsigned)dr < 128u;
    const int rtd = dg ? (dr >> 5) : -1;

    __builtin_amdgcn_s_setprio(1);
    f32x16 acc0 = MFMA_(a[0], b[0][0], kZ, 0, 0, 0);
    f32x16 acc1 = MFMA_(a[0], b[1][0], kZ, 0, 0, 0);
#pragma unroll
    for (int ks = 1; ks < 8; ++ks) {
      acc0 = MFMA_(a[ks], b[0][ks], acc0, 0, 0, 0);
      acc1 = MFMA_(a[ks], b[1][ks], acc1, 0, 0, 0);
    }
    __builtin_amdgcn_s_setprio(0);
    if (!dg) {
      expAcc<false>(acc0, s[0], -1, hi);
      expAcc<false>(acc1, s[1], -1, hi);
    } else {
      expAcc<true>(acc0, s[0], rtd == 0 ? lo : -1, hi);
      expAcc<true>(acc1, s[1], rtd == 1 ? lo : -1, hi);
    }

    __builtin_amdgcn_s_setprio(1);
    acc0 = MFMA_(a[0], b[2][0], kZ, 0, 0, 0);
    acc1 = MFMA_(a[0], b[3][0], kZ, 0, 0, 0);
#pragma unroll
    for (int ks = 1; ks < 8; ++ks) {
      acc0 = MFMA_(a[ks], b[2][ks], acc0, 0, 0, 0);
      acc1 = MFMA_(a[ks], b[3][ks], acc1, 0, 0, 0);
    }
    __builtin_amdgcn_s_setprio(0);

    if (it + 1 < 32) {
      const unsigned short* ap = abase + (size_t)(it + 1) * 4096;
#pragma unroll
      for (int ks = 0; ks < 8; ++ks)
        a[ks] = *reinterpret_cast<const bf16x8*>(ap + ks * 512);
    }

    if (!dg) {
      expAcc<false>(acc0, s[2], -1, hi);
      expAcc<false>(acc1, s[3], -1, hi);
    } else {
      expAcc<true>(acc0, s[2], rtd == 2 ? lo : -1, hi);
      expAcc<true>(acc1, s[3], rtd == 3 ? lo : -1, hi);
    }
  }

#pragma unroll
  for (int rt = 0; rt < 4; ++rt) {
    float v = s[rt].x + s[rt].y;
    v += __shfl_xor(v, 32, 64);
    if (hi == 0) atomicAdd(&S[row0w + rt * 32 + lo], v);
  }

  // ================= phase 3: last-block finalization =================
  asm volatile("s_waitcnt vmcnt(0)" ::: "memory");   // drain S atomics (per wave)
  __syncthreads();
  __shared__ unsigned int lastFlag;
  if (threadIdx.x == 0) {
    unsigned int old = __hip_atomic_fetch_add(&cnt[2], 1u, __ATOMIC_RELAXED,
                                              __HIP_MEMORY_SCOPE_AGENT);
    lastFlag = (old == (unsigned)(MAINB - 1)) ? 1u : 0u;
  }
  __syncthreads();
  if (lastFlag) {
    __builtin_amdgcn_fence(__ATOMIC_ACQUIRE, "agent");  // see all S / Pp
    const int t = threadIdx.x;          // 256 threads, float4 strides
    float q = 0.f;
    const float4* S4 = reinterpret_cast<const float4*>(S);
    for (int i = t; i < NROWS / 4; i += 256) {
      float4 sv = S4[i];
      q += LN2 * (4.0f * MSHIFT + __log2f(sv.x) + __log2f(sv.y) +
                  __log2f(sv.z) + __log2f(sv.w));
    }
    const float4* P4 = reinterpret_cast<const float4*>(Pp);
    for (int i = t; i < NCHUNK / 4; i += 256) {
      float4 p = P4[i];
      q -= 4.0f * (p.x + p.y + p.z + p.w);
    }
    __shared__ float redf[256];
    redf[t] = q;
    __syncthreads();
    for (int s2 = 128; s2 > 0; s2 >>= 1) {
      if (t < s2) redf[t] += redf[t + s2];
      __syncthreads();
    }
    if (t == 0) out[0] = redf[0] / (float)NROWS;
  }
}

// ---------------------------------------------------------------------------
extern "C" void kernel_launch(void* const* d_in, const int* in_sizes, int n_in,
                              void* d_out, int out_size, void* d_ws, size_t ws_size,
                              hipStream_t stream) {
  const float* zi = (const float*)d_in[0];
  const float* zj = (const float*)d_in[1];
  unsigned short* zbF = (unsigned short*)d_ws;                     // 4 MB
  float* S  = (float*)((char*)d_ws + (size_t)NROWS * DDIM * 2);    // 64 KB
  float* Pp = S + NROWS;                                           // 8 KB
  unsigned int* cnt = (unsigned int*)(Pp + NCHUNK);                // 12 B
  float* out = (float*)d_out;

  hipMemsetAsync(cnt, 0, 3 * sizeof(unsigned int), stream);        // replay-safe
  hipLaunchKernelGGL(k_all, dim3(MAINB), dim3(256), 0, stream,
                     zi, zj, zbF, S, Pp, cnt, out);
}

// Round 12
// 132.434 us; speedup vs baseline: 1.5858x; 1.5858x over previous
//
#include <hip/hip_runtime.h>

#define TEMP    0.5f
#define LOG2E   1.4426950408889634f
#define C2      (LOG2E / TEMP)        /* t = dot * C2 */
#define MSHIFT  160.0f                /* fixed base-2 softmax shift */
#define LN2     0.6931471805599453f
#define NROWS   16384
#define BHALF   8192
#define DDIM    128
#define PREPB   2048                  /* k_prep blocks = 524288/256 */

typedef __bf16 bf16x8 __attribute__((ext_vector_type(8)));
typedef float  f32x16 __attribute__((ext_vector_type(16)));
typedef float  f32x2  __attribute__((ext_vector_type(2)));

__device__ __forceinline__ float fexp2(float x) {
#if __has_builtin(__builtin_amdgcn_exp2f)
  return __builtin_amdgcn_exp2f(x);
#else
  return exp2f(x);
#endif
}

__device__ __forceinline__ unsigned short f2bf(float f) {
  unsigned int u = __float_as_uint(f);
  unsigned int r = (u + 0x7FFFu + ((u >> 16) & 1u)) >> 16;  // RNE
  return (unsigned short)r;
}

// ---------------------------------------------------------------------------
// zbF frag-major layout: for row r, k-index k:
//   g = r/32, lo = r%32, khi = k/8, j = k%8
//   short index = g*4096 + khi*256 + lo*8 + j
// A wave's frag load (fixed ks): 64 lanes read a contiguous 1KB block.
// ---------------------------------------------------------------------------

// k_prep: cast concat(z_i,z_j) fp32->bf16 into frag-major zbF; per-block
// partial dot(z_i,z_j) -> Pp[block]; zero S.
__global__ void k_prep(const float* __restrict__ zi, const float* __restrict__ zj,
                       unsigned short* __restrict__ zbF,
                       float* __restrict__ S, float* __restrict__ Pp) {
  const int t   = blockIdx.x * 256 + threadIdx.x;   // 0..524287 float4 groups
  const int row = t >> 5;                           // 32 float4 per 128-elt row
  const int k0  = (t & 31) * 4;
  const float* src = (row < BHALF) ? (zi + (size_t)row * DDIM)
                                   : (zj + (size_t)(row - BHALF) * DDIM);
  float4 v = *reinterpret_cast<const float4*>(src + k0);

  const int g = row >> 5, lo = row & 31, khi = k0 >> 3, j0 = k0 & 7;
  ushort4 o;
  o.x = f2bf(v.x); o.y = f2bf(v.y); o.z = f2bf(v.z); o.w = f2bf(v.w);
  *reinterpret_cast<ushort4*>(zbF + (size_t)g * 4096 + khi * 256 + lo * 8 + j0) = o;

  float dot = 0.f;
  if (row < BHALF) {
    float4 w = *reinterpret_cast<const float4*>(zj + (size_t)row * DDIM + k0);
    dot = fmaf(v.x, w.x, fmaf(v.y, w.y, fmaf(v.z, w.z, v.w * w.w)));
  }
#pragma unroll
  for (int m = 32; m >= 1; m >>= 1) dot += __shfl_xor(dot, m, 64);
  __shared__ float red[4];
  if ((threadIdx.x & 63) == 0) red[threadIdx.x >> 6] = dot;
  __syncthreads();
  if (threadIdx.x == 0) Pp[blockIdx.x] = red[0] + red[1] + red[2] + red[3];

  if (t < NROWS) S[t] = 0.f;
}

// ---------------------------------------------------------------------------
// k_main: wave holds 128 persistent rows as MFMA *B* operand (lane-indexed in
// C/D -> scalar row sums). Streams 32-col tiles as the A operand, coalesced
// frag loads from frag-major zbF. Single-buffer pipelined reload under the
// exp section. No LDS, no barriers. Structure = r4's measured-best 73.5us.
//
// Round-12 = round-11 resubmitted unchanged (infra "container failed twice",
// same as round 1; kernel audited — bounded s_sleep, no sync dependency, no
// hang path). Single delta vs r4: anti-phase stagger keyed on
// (blockIdx>>8)&1. Co-resident blocks on a CU are i and i+256 (512 blocks /
// 256 CUs), so r4's (blockIdx^wave)&1 parity was IDENTICAL for both waves of
// every SIMD — the r4 sleep was a no-op and anti-phase was never tested.
// s_sleep(7) ~ 448 cyc ~ half an iteration.
// FROZEN lessons: no exp/MFMA source interleave (r1/r2/r5 spill); no thin
// waves (r6 +17us); no kC C-operand (r9 +3.5us); no fused phases / software
// barriers (r7/r8/r10 cache-coherence storms, +21..+90us).
// ---------------------------------------------------------------------------
template <bool MASK>
__device__ __forceinline__ void expAcc(const f32x16& acc, f32x2& s, int d, int hi) {
#pragma unroll
  for (int k = 0; k < 8; ++k) {
    f32x2 u;
    u.x = acc[2 * k];
    u.y = acc[2 * k + 1];
    const f32x2 c2v = {C2, C2};
    const f32x2 msv = {-MSHIFT, -MSHIFT};
    u = __builtin_elementwise_fma(u, c2v, msv);       // v_pk_fma_f32
    f32x2 e;
    e.x = fexp2(u.x);
    e.y = fexp2(u.y);
    if (MASK) {
      const int r0 = 2 * k, r1 = 2 * k + 1;
      if (((r0 & 3) + 8 * (r0 >> 2) + 4 * hi) == d) e.x = 0.f;  // C/D reg map
      if (((r1 & 3) + 8 * (r1 >> 2) + 4 * hi) == d) e.y = 0.f;
    }
    s += e;                                            // v_pk_add_f32
  }
}

#define MFMA_ __builtin_amdgcn_mfma_f32_32x32x16_bf16

__global__ __launch_bounds__(256, 2)
void k_main(const unsigned short* __restrict__ zbF, float* __restrict__ S) {
  const int wave = threadIdx.x >> 6;
  const int lane = threadIdx.x & 63;
  const int lo = lane & 31;
  const int hi = lane >> 5;
  const int rb = blockIdx.x & 31;       // 32 row blocks of 512 rows
  const int cc = blockIdx.x >> 5;       // 16 col chunks of 1024 cols
  const int row0w = rb * 512 + wave * 128;

  // persistent row frags (B operand): 4 row-tiles x 8 k-steps = 128 VGPRs
  bf16x8 b[4][8];
#pragma unroll
  for (int rt = 0; rt < 4; ++rt) {
    const unsigned short* bp = zbF + (size_t)((row0w >> 5) + rt) * 4096 + hi * 256 + lo * 8;
#pragma unroll
    for (int ks = 0; ks < 8; ++ks)
      b[rt][ks] = *reinterpret_cast<const bf16x8*>(bp + ks * 512);
  }

  const f32x16 kZ = {};                 // persistent zero C-operand
  f32x2 s[4];
#pragma unroll
  for (int rt = 0; rt < 4; ++rt) { s[rt].x = 0.f; s[rt].y = 0.f; }

  const int c0base = cc * 1024;
  const unsigned short* abase = zbF + (size_t)(c0base >> 5) * 4096 + hi * 256 + lo * 8;

  bf16x8 a[8];
#pragma unroll
  for (int ks = 0; ks < 8; ++ks)
    a[ks] = *reinterpret_cast<const bf16x8*>(abase + ks * 512);

  // anti-phase stagger: co-resident blocks on a CU are i and i+256, so key
  // on blockIdx bit 8. Half the SIMD's waves start ~448 cyc (half-iteration)
  // late -> their MFMA sections overlap the partner's exp sections.
  if (((blockIdx.x >> 8) & 1) != 0) __builtin_amdgcn_s_sleep(7);

  for (int it = 0; it < 32; ++it) {
    const int c0 = c0base + it * 32;
    const int dr = c0 - row0w;
    const bool dg = (unsigned)dr < 128u;       // tile touches diagonal?
    const int rtd = dg ? (dr >> 5) : -1;

    // half 1: row-tiles 0,1
    __builtin_amdgcn_s_setprio(1);
    f32x16 acc0 = MFMA_(a[0], b[0][0], kZ, 0, 0, 0);
    f32x16 acc1 = MFMA_(a[0], b[1][0], kZ, 0, 0, 0);
#pragma unroll
    for (int ks = 1; ks < 8; ++ks) {
      acc0 = MFMA_(a[ks], b[0][ks], acc0, 0, 0, 0);
      acc1 = MFMA_(a[ks], b[1][ks], acc1, 0, 0, 0);
    }
    __builtin_amdgcn_s_setprio(0);
    if (!dg) {
      expAcc<false>(acc0, s[0], -1, hi);
      expAcc<false>(acc1, s[1], -1, hi);
    } else {
      expAcc<true>(acc0, s[0], rtd == 0 ? lo : -1, hi);
      expAcc<true>(acc1, s[1], rtd == 1 ? lo : -1, hi);
    }

    // half 2: row-tiles 2,3
    __builtin_amdgcn_s_setprio(1);
    acc0 = MFMA_(a[0], b[2][0], kZ, 0, 0, 0);
    acc1 = MFMA_(a[0], b[3][0], kZ, 0, 0, 0);
#pragma unroll
    for (int ks = 1; ks < 8; ++ks) {
      acc0 = MFMA_(a[ks], b[2][ks], acc0, 0, 0, 0);
      acc1 = MFMA_(a[ks], b[3][ks], acc1, 0, 0, 0);
    }
    __builtin_amdgcn_s_setprio(0);

    // pipelined single-buffer reload: a[] free after the chains above; the
    // vmcnt wait lands after the exp section below.
    if (it + 1 < 32) {
      const unsigned short* ap = abase + (size_t)(it + 1) * 4096;
#pragma unroll
      for (int ks = 0; ks < 8; ++ks)
        a[ks] = *reinterpret_cast<const bf16x8*>(ap + ks * 512);
    }

    if (!dg) {
      expAcc<false>(acc0, s[2], -1, hi);
      expAcc<false>(acc1, s[3], -1, hi);
    } else {
      expAcc<true>(acc0, s[2], rtd == 2 ? lo : -1, hi);
      expAcc<true>(acc1, s[3], rtd == 3 ? lo : -1, hi);
    }
  }

  // row sums: lane-local scalar + fold hi halves, one atomic per row per chunk
#pragma unroll
  for (int rt = 0; rt < 4; ++rt) {
    float v = s[rt].x + s[rt].y;
    v += __shfl_xor(v, 32, 64);
    if (hi == 0) atomicAdd(&S[row0w + rt * 32 + lo], v);
  }
}

// ---------------------------------------------------------------------------
// k_fin: out = ( LN2 * sum_k (M + log2 S_k)  -  4 * sum Pp ) / N
// Linear -> single fused block reduction (1024 threads).
// ---------------------------------------------------------------------------
__global__ void k_fin(const float* __restrict__ S, const float* __restrict__ Pp,
                      float* __restrict__ out) {
  const int t = threadIdx.x;            // 1024 threads
  float q = 0.f;
  for (int r = t; r < NROWS; r += 1024)
    q += LN2 * (MSHIFT + __log2f(S[r]));
  for (int r = t; r < PREPB; r += 1024)
    q -= 4.0f * Pp[r];
  __shared__ float red[1024];
  red[t] = q;
  __syncthreads();
  for (int s2 = 512; s2 > 0; s2 >>= 1) {
    if (t < s2) red[t] += red[t + s2];
    __syncthreads();
  }
  if (t == 0) out[0] = red[0] / (float)NROWS;
}

// ---------------------------------------------------------------------------
extern "C" void kernel_launch(void* const* d_in, const int* in_sizes, int n_in,
                              void* d_out, int out_size, void* d_ws, size_t ws_size,
                              hipStream_t stream) {
  const float* zi = (const float*)d_in[0];
  const float* zj = (const float*)d_in[1];
  unsigned short* zbF = (unsigned short*)d_ws;                     // 4 MB
  float* S  = (float*)((char*)d_ws + (size_t)NROWS * DDIM * 2);    // 64 KB
  float* Pp = S + NROWS;                                           // 8 KB
  float* out = (float*)d_out;

  hipLaunchKernelGGL(k_prep, dim3(PREPB), dim3(256), 0, stream, zi, zj, zbF, S, Pp);
  hipLaunchKernelGGL(k_main, dim3(512),  dim3(256), 0, stream, zbF, S);
  hipLaunchKernelGGL(k_fin,  dim3(1),    dim3(1024), 0, stream, S, Pp, out);
}